// Round 6
// baseline (172.839 us; speedup 1.0000x reference)
//
#include <hip/hip_runtime.h>
#include <hip/hip_bf16.h>

#define B_    4
#define CIN_  64
#define H_    128
#define W_    128
#define COUT_ 64
#define KK_   9
#define OFFC_ 18
#define HW_   (H_*W_)
#define TILE_ 32
#define PW_   34      // patch cols = TILE_+2

typedef short bf8  __attribute__((ext_vector_type(8)));   // 8 bf16 (4 VGPRs)
typedef float f32x4 __attribute__((ext_vector_type(4)));

__device__ inline short f2bf(float f) {
    union { __hip_bfloat16 h; short s; } u; u.h = __float2bfloat16(f); return u.s;
}
__device__ inline float bf2f(short s) {
    union { unsigned u; float f; } v; v.u = ((unsigned)(unsigned short)s) << 16; return v.f;
}

// ---------------------------------------------------------------------------
// Prep (single launch): blocks 0..1023 transpose x -> NHWC bf16;
// blocks 1024..1167 repack weights to bf16 MFMA layout.
//   xt[b][y][x][c]   dwbf[k][o][c] (9*64*64)   owbf[k][co<32][c] (pad rows 0)
// ---------------------------------------------------------------------------
__global__ __launch_bounds__(256) void prep_all(
    const float* __restrict__ x,
    const float* __restrict__ ow, const float* __restrict__ dw,
    short* __restrict__ xt, short* __restrict__ dwbf, short* __restrict__ owbf)
{
    const int tid = threadIdx.x;
    const int bid = blockIdx.x;
    if (bid < 1024) {
        const int b  = bid >> 8;
        const int pb = bid & 255;
        const int p  = tid & 63;
        const int g  = tid >> 6;             // channel group 0..3 (16 ch)
        const int pix = pb * 64 + p;
        const float* src = x + ((size_t)b * CIN_ + g * 16) * HW_ + pix;
        short vals[16];
        #pragma unroll
        for (int j = 0; j < 16; ++j) vals[j] = f2bf(src[(size_t)j * HW_]);
        short* dst = xt + ((size_t)b * HW_ + pix) * 64 + g * 16;
        *(bf8*)dst       = *(bf8*)&vals[0];
        *(bf8*)(dst + 8) = *(bf8*)&vals[8];
    } else {
        const int idx = (bid - 1024) * 256 + tid;   // 0..36863
        {   // dwbf: 9*64*64 = 36864
            const int k = idx / (COUT_ * CIN_);
            const int r = idx % (COUT_ * CIN_);
            const int o = r >> 6, c = r & 63;
            dwbf[idx] = f2bf(dw[(o * CIN_ + c) * KK_ + k]);
        }
        if (idx < KK_ * 32 * CIN_) {                // 18432
            const int k = idx / (32 * CIN_);
            const int r = idx % (32 * CIN_);
            const int co = r >> 6, c = r & 63;
            owbf[idx] = f2bf(co < OFFC_ ? ow[(co * CIN_ + c) * KK_ + k] : 0.0f);
        }
    }
}

// ---------------------------------------------------------------------------
// Fused kernel. Block = 256 thr (4 waves) = 32 pixels, grid (512,4) = 2048
// blocks -> 8 blocks/CU, 32 waves/CU. LDS rows [row][c] bf16, chunk-XOR
// swizzle: elem(row,c) = row*64 + (((c>>3) ^ (row&7))<<3) + (c&7).
// ---------------------------------------------------------------------------
__global__ __launch_bounds__(256, 8) void fused_deform_mfma(
    const short* __restrict__ xt,    // (B,HW,64) bf16 channels-last
    const short* __restrict__ owbf,  // [9][32][64] bf16
    const float* __restrict__ obias, // (18,)
    const short* __restrict__ dwbf,  // [9][64][64] bf16
    const float* __restrict__ dbias, // (64,)
    float* __restrict__ out)         // (B,64,128,128) f32
{
    __shared__ union {
        short xtl[3 * PW_ * 64];     // phase A: [y][q][c], q = col+1 (13.1 KB)
        short smp[2 * TILE_ * 64];   // phase B: [buf][p][c]           (8 KB)
    } u;
    __shared__ float offs[OFFC_ * TILE_];

    const int tid = threadIdx.x;
    const int b   = blockIdx.y;
    const int pixbase = blockIdx.x * TILE_;
    const int ho    = pixbase >> 7;
    const int wbase = pixbase & (W_ - 1);
    const int lane  = tid & 63;
    const int wv    = tid >> 6;              // wave 0..3
    const int arow  = lane & 15;             // MFMA frag row/col index
    const int kseg  = lane >> 4;             // 0..3

    const short* xbt = xt + (size_t)b * HW_ * 64;

    // ---- stage x patch (3 rows x 34 cols x 64 ch) once, swizzled ----
    for (int base = 0; base < 1024; base += 256) {
        const int idx = base + tid;
        if (idx < 3 * PW_ * 8) {
            const int cc = idx & 7;          // c-chunk
            const int qy = idx >> 3;         // 0..101
            const int y  = qy / PW_;
            const int q  = qy - y * PW_;
            const int gy = ho + y - 1;
            const int gx = wbase + q - 1;
            bf8 v;
            if (gy >= 0 && gy < H_ && gx >= 0 && gx < W_) {
                v = *(const bf8*)&xbt[(size_t)(gy * W_ + gx) * 64 + cc * 8];
            } else {
                #pragma unroll
                for (int j = 0; j < 8; ++j) v[j] = 0;
            }
            *(bf8*)&u.xtl[(y * PW_ + q) * 64 + ((cc ^ (q & 7)) << 3)] = v;
        }
    }
    __syncthreads();

    // ---- Phase A: offset conv via MFMA ----
    {
        const int m = wv & 1;                // co tile (0/1)
        const int h = wv >> 1;               // pixel half (16 px each)
        f32x4 acca = (f32x4)0.f;
        for (int t = 0; t < KK_; ++t) {
            const int ky = t / 3, kx = t % 3;
            #pragma unroll
            for (int kc = 0; kc < 2; ++kc) {
                const int cbase = kc * 32 + kseg * 8;
                const bf8 afrag = *(const bf8*)&owbf[(t * 32 + m * 16 + arow) * 64 + cbase];
                const int cchunk = cbase >> 3;
                const int pp = h * 16 + arow;
                const int q  = pp + kx;
                const bf8 bfrag = *(const bf8*)&u.xtl[(ky * PW_ + q) * 64 + ((cchunk ^ (q & 7)) << 3)];
                acca = __builtin_amdgcn_mfma_f32_16x16x32_bf16(afrag, bfrag, acca, 0, 0, 0);
            }
        }
        #pragma unroll
        for (int r = 0; r < 4; ++r) {
            const int co = m * 16 + kseg * 4 + r;
            if (co < OFFC_) {
                const int pp = h * 16 + arow;
                offs[co * TILE_ + pp] = acca[r] + obias[co];
            }
        }
    }
    __syncthreads();   // offs ready; xtl dead -> smp may reuse the union

    // ---- Phase B: deformable conv, double-buffered smp ----
    const int p  = lane & 31;                // staging pixel (2 lanes/pixel)
    const int cg = lane >> 5;                // chunk half (4 chunks each)
    const int wo = wbase + p;

    auto stageB = [&](int t, int dstbuf) {
        const int ky = t / 3, kx = t % 3;
        const float dy = offs[(2 * t + 0) * TILE_ + p];
        const float dx = offs[(2 * t + 1) * TILE_ + p];
        const float ys = (float)(ho + ky - 1) + dy;
        const float xs = (float)(wo + kx - 1) + dx;
        const float y0f = floorf(ys), x0f = floorf(xs);
        const float ly = ys - y0f, lx = xs - x0f;
        const int y0 = (int)y0f, x0 = (int)x0f;
        const int y1 = y0 + 1,   x1 = x0 + 1;
        const bool y0v = (y0 >= 0) & (y0 < H_);
        const bool y1v = (y1 >= 0) & (y1 < H_);
        const bool x0v = (x0 >= 0) & (x0 < W_);
        const bool x1v = (x1 >= 0) & (x1 < W_);
        const float m00 = (y0v & x0v) ? (1.f - ly) * (1.f - lx) : 0.f;
        const float m01 = (y0v & x1v) ? (1.f - ly) * lx         : 0.f;
        const float m10 = (y1v & x0v) ? ly * (1.f - lx)         : 0.f;
        const float m11 = (y1v & x1v) ? ly * lx                 : 0.f;
        const int y0c = min(max(y0, 0), H_ - 1);
        const int y1c = min(max(y1, 0), H_ - 1);
        const int x0c = min(max(x0, 0), W_ - 1);
        const int x1c = min(max(x1, 0), W_ - 1);
        const short* c00 = xbt + (size_t)(y0c * W_ + x0c) * 64;
        const short* c01 = xbt + (size_t)(y0c * W_ + x1c) * 64;
        const short* c10 = xbt + (size_t)(y1c * W_ + x0c) * 64;
        const short* c11 = xbt + (size_t)(y1c * W_ + x1c) * 64;
        #pragma unroll
        for (int j = 0; j < 4; ++j) {
            const int chunk = cg * 4 + j;
            const int co8 = chunk * 8;
            const bf8 v00 = *(const bf8*)(c00 + co8);
            const bf8 v01 = *(const bf8*)(c01 + co8);
            const bf8 v10 = *(const bf8*)(c10 + co8);
            const bf8 v11 = *(const bf8*)(c11 + co8);
            bf8 v;
            #pragma unroll
            for (int jj = 0; jj < 8; ++jj) {
                const float s = m00 * bf2f(v00[jj]) + m01 * bf2f(v01[jj])
                              + m10 * bf2f(v10[jj]) + m11 * bf2f(v11[jj]);
                v[jj] = f2bf(s);
            }
            *(bf8*)&u.smp[dstbuf * (TILE_ * 64) + p * 64 + ((chunk ^ (p & 7)) << 3)] = v;
        }
    };

    f32x4 accb[2];
    accb[0] = (f32x4)0.f; accb[1] = (f32x4)0.f;

    int buf = 0;
    stageB(0, 0);
    __syncthreads();
    for (int t = 0; t < KK_; ++t) {
        if (t < KK_ - 1) stageB(t + 1, buf ^ 1);
        #pragma unroll
        for (int kc = 0; kc < 2; ++kc) {
            const int cbase = kc * 32 + kseg * 8;
            const bf8 afrag = *(const bf8*)&dwbf[(t * 64 + wv * 16 + arow) * 64 + cbase];
            const int cchunk = cbase >> 3;
            #pragma unroll
            for (int nt = 0; nt < 2; ++nt) {
                const int pp = nt * 16 + arow;
                const bf8 bfrag = *(const bf8*)&u.smp[buf * (TILE_ * 64) + pp * 64 + ((cchunk ^ (pp & 7)) << 3)];
                accb[nt] = __builtin_amdgcn_mfma_f32_16x16x32_bf16(afrag, bfrag, accb[nt], 0, 0, 0);
            }
        }
        __syncthreads();
        buf ^= 1;
    }

    // ---- epilogue: o = wv*16 + kseg*4 + r, pixel = pixbase + pp ----
    float* ob = out + (size_t)b * COUT_ * HW_ + pixbase;
    #pragma unroll
    for (int nt = 0; nt < 2; ++nt) {
        const int pp = nt * 16 + arow;
        #pragma unroll
        for (int r = 0; r < 4; ++r) {
            const int o = wv * 16 + kseg * 4 + r;
            ob[(size_t)o * HW_ + pp] = accb[nt][r] + dbias[o];
        }
    }
}

extern "C" void kernel_launch(void* const* d_in, const int* in_sizes, int n_in,
                              void* d_out, int out_size, void* d_ws, size_t ws_size,
                              hipStream_t stream) {
    const float* x        = (const float*)d_in[0];
    const float* offset_w = (const float*)d_in[1];
    const float* offset_b = (const float*)d_in[2];
    const float* deform_w = (const float*)d_in[3];
    const float* deform_b = (const float*)d_in[4];
    float* out = (float*)d_out;

    short* dwbf = (short*)d_ws;                        // 73728 B
    short* owbf = (short*)((char*)d_ws + 73728);       // 36864 B
    short* xt   = (short*)((char*)d_ws + 110592);      // 8 MB NHWC bf16

    prep_all<<<1024 + 144, 256, 0, stream>>>(x, offset_w, deform_w, xt, dwbf, owbf);

    dim3 grid(HW_ / TILE_, B_);
    fused_deform_mfma<<<grid, 256, 0, stream>>>(xt, owbf, offset_b, dwbf, deform_b, out);
}

// Round 7
// 106.970 us; speedup vs baseline: 1.6158x; 1.6158x over previous
//
#include <hip/hip_runtime.h>
#include <hip/hip_bf16.h>

#define B_    4
#define CIN_  64
#define H_    128
#define W_    128
#define COUT_ 64
#define KK_   9
#define OFFC_ 18
#define HW_   (H_*W_)
#define TILE_ 64

typedef short bf8  __attribute__((ext_vector_type(8)));   // 8 bf16 (4 VGPRs)
typedef float f32x4 __attribute__((ext_vector_type(4)));

__device__ inline short f2bf(float f) {
    union { __hip_bfloat16 h; short s; } u; u.h = __float2bfloat16(f); return u.s;
}
__device__ inline float bf2f(short s) {
    union { unsigned u; float f; } v; v.u = ((unsigned)(unsigned short)s) << 16; return v.f;
}

// ---------------------------------------------------------------------------
// Prep (single launch): blocks 0..1023 transpose x -> NHWC bf16;
// blocks 1024..1167 repack weights to bf16 MFMA layout.
//   xt[b][y][x][c]   dwbf[k][o][c] (9*64*64)   owbf[k][co<32][c] (pad rows 0)
// ---------------------------------------------------------------------------
__global__ __launch_bounds__(256) void prep_all(
    const float* __restrict__ x,
    const float* __restrict__ ow, const float* __restrict__ dw,
    short* __restrict__ xt, short* __restrict__ dwbf, short* __restrict__ owbf)
{
    const int tid = threadIdx.x;
    const int bid = blockIdx.x;
    if (bid < 1024) {
        const int b  = bid >> 8;
        const int pb = bid & 255;
        const int p  = tid & 63;
        const int g  = tid >> 6;             // channel group 0..3 (16 ch)
        const int pix = pb * 64 + p;
        const float* src = x + ((size_t)b * CIN_ + g * 16) * HW_ + pix;
        short vals[16];
        #pragma unroll
        for (int j = 0; j < 16; ++j) vals[j] = f2bf(src[(size_t)j * HW_]);
        short* dst = xt + ((size_t)b * HW_ + pix) * 64 + g * 16;
        *(bf8*)dst       = *(bf8*)&vals[0];
        *(bf8*)(dst + 8) = *(bf8*)&vals[8];
    } else {
        const int idx = (bid - 1024) * 256 + tid;   // 0..36863
        {   // dwbf: 9*64*64 = 36864
            const int k = idx / (COUT_ * CIN_);
            const int r = idx % (COUT_ * CIN_);
            const int o = r >> 6, c = r & 63;
            dwbf[idx] = f2bf(dw[(o * CIN_ + c) * KK_ + k]);
        }
        if (idx < KK_ * 32 * CIN_) {                // 18432
            const int k = idx / (32 * CIN_);
            const int r = idx % (32 * CIN_);
            const int co = r >> 6, c = r & 63;
            owbf[idx] = f2bf(co < OFFC_ ? ow[(co * CIN_ + c) * KK_ + k] : 0.0f);
        }
    }
}

// ---------------------------------------------------------------------------
// Fused kernel, ZERO LDS / ZERO barriers. Block = 256 thr (4 waves); each
// wave owns 16 pixels x all 64 out channels. Lane (arow = pixel-in-16,
// kseg = channel segment) builds MFMA B-fragments straight from NHWC global.
// Phase A: offset conv via MFMA, offsets stay in registers, dy/dx fetched
// per tap with two __shfl broadcasts. Phase B: bilinear-sample -> B-frag in
// regs -> 8 MFMA per tap. grid (HW/64, B) = 1024 blocks.
// ---------------------------------------------------------------------------
__global__ __launch_bounds__(256, 4) void fused_deform_mfma(
    const short* __restrict__ xt,    // (B,HW,64) bf16 channels-last
    const short* __restrict__ owbf,  // [9][32][64] bf16
    const float* __restrict__ obias, // (18,)
    const short* __restrict__ dwbf,  // [9][64][64] bf16
    const float* __restrict__ dbias, // (64,)
    float* __restrict__ out)         // (B,64,128,128) f32
{
    const int tid  = threadIdx.x;
    const int b    = blockIdx.y;
    const int pixbase = blockIdx.x * TILE_;
    const int ho   = pixbase >> 7;
    const int wbase= pixbase & (W_ - 1);
    const int lane = tid & 63;
    const int wv   = tid >> 6;               // wave 0..3
    const int arow = lane & 15;              // my pixel within wave's 16
    const int kseg = lane >> 4;              // channel segment 0..3
    const int wo   = wbase + wv * 16 + arow; // my pixel's x coordinate
    const int pix  = pixbase + wv * 16 + arow;

    const short* xbt = xt + (size_t)b * HW_ * 64;

    // ---------------- Phase A: offset conv (per-wave, from global) --------
    f32x4 acca[2];
    acca[0] = (f32x4)0.f; acca[1] = (f32x4)0.f;
    #pragma unroll
    for (int t = 0; t < KK_; ++t) {
        const int ky = t / 3, kx = t % 3;
        const int gy = ho + ky - 1;
        const int gx = wo + kx - 1;
        const bool v = (gy >= 0) & (gy < H_) & (gx >= 0) & (gx < W_);
        const short* bp = xbt + (size_t)(gy * W_ + gx) * 64 + kseg * 8;
        #pragma unroll
        for (int kc = 0; kc < 2; ++kc) {
            bf8 bfrag;
            if (v) bfrag = *(const bf8*)(bp + kc * 32);
            else { bfrag = (bf8)0; }
            const short* ap = owbf + (size_t)(t * 32 + arow) * 64 + kc * 32 + kseg * 8;
            const bf8 a0 = *(const bf8*)(ap);
            const bf8 a1 = *(const bf8*)(ap + 16 * 64);
            acca[0] = __builtin_amdgcn_mfma_f32_16x16x32_bf16(a0, bfrag, acca[0], 0, 0, 0);
            acca[1] = __builtin_amdgcn_mfma_f32_16x16x32_bf16(a1, bfrag, acca[1], 0, 0, 0);
        }
    }
    // add offset bias: lane holds co = m*16 + kseg*4 + r for pixel arow
    #pragma unroll
    for (int m = 0; m < 2; ++m)
        #pragma unroll
        for (int r = 0; r < 4; ++r) {
            const int co = m * 16 + kseg * 4 + r;
            if (co < OFFC_) acca[m][r] += obias[co];
        }

    // ---------------- Phase B: deformable conv (per-wave, barrier-free) ---
    f32x4 oacc[4];
    #pragma unroll
    for (int m = 0; m < 4; ++m) oacc[m] = (f32x4)0.f;

    #pragma unroll
    for (int t = 0; t < KK_; ++t) {
        const int ky = t / 3, kx = t % 3;
        // dy,dx for my pixel: broadcast from the lane that holds co=2t,2t+1
        float dy, dx;
        if (t < 8) {
            const int skl = (t >> 1) * 16 + arow;
            dy = __shfl(acca[0][(2 * t) & 3],     skl);
            dx = __shfl(acca[0][(2 * t + 1) & 3], skl);
        } else {
            dy = __shfl(acca[1][0], arow);
            dx = __shfl(acca[1][1], arow);
        }
        const float ys = (float)(ho + ky - 1) + dy;
        const float xs = (float)(wo + kx - 1) + dx;
        const float y0f = floorf(ys), x0f = floorf(xs);
        const float ly = ys - y0f, lx = xs - x0f;
        const int y0 = (int)y0f, x0 = (int)x0f;
        const int y1 = y0 + 1,   x1 = x0 + 1;
        const bool y0v = (y0 >= 0) & (y0 < H_);
        const bool y1v = (y1 >= 0) & (y1 < H_);
        const bool x0v = (x0 >= 0) & (x0 < W_);
        const bool x1v = (x1 >= 0) & (x1 < W_);
        const float m00 = (y0v & x0v) ? (1.f - ly) * (1.f - lx) : 0.f;
        const float m01 = (y0v & x1v) ? (1.f - ly) * lx         : 0.f;
        const float m10 = (y1v & x0v) ? ly * (1.f - lx)         : 0.f;
        const float m11 = (y1v & x1v) ? ly * lx                 : 0.f;
        const int y0c = min(max(y0, 0), H_ - 1);
        const int y1c = min(max(y1, 0), H_ - 1);
        const int x0c = min(max(x0, 0), W_ - 1);
        const int x1c = min(max(x1, 0), W_ - 1);
        const short* c00 = xbt + (size_t)(y0c * W_ + x0c) * 64 + kseg * 8;
        const short* c01 = xbt + (size_t)(y0c * W_ + x1c) * 64 + kseg * 8;
        const short* c10 = xbt + (size_t)(y1c * W_ + x0c) * 64 + kseg * 8;
        const short* c11 = xbt + (size_t)(y1c * W_ + x1c) * 64 + kseg * 8;

        // 8 independent 16 B loads (my 16 channels x 4 corners)
        const bf8 v00a = *(const bf8*)(c00);  const bf8 v00b = *(const bf8*)(c00 + 32);
        const bf8 v01a = *(const bf8*)(c01);  const bf8 v01b = *(const bf8*)(c01 + 32);
        const bf8 v10a = *(const bf8*)(c10);  const bf8 v10b = *(const bf8*)(c10 + 32);
        const bf8 v11a = *(const bf8*)(c11);  const bf8 v11b = *(const bf8*)(c11 + 32);

        // bilinear combine -> two B-fragments (kc = 0,1)
        bf8 bf0, bf1;
        #pragma unroll
        for (int j = 0; j < 8; ++j) {
            const float s0 = m00 * bf2f(v00a[j]) + m01 * bf2f(v01a[j])
                           + m10 * bf2f(v10a[j]) + m11 * bf2f(v11a[j]);
            const float s1 = m00 * bf2f(v00b[j]) + m01 * bf2f(v01b[j])
                           + m10 * bf2f(v10b[j]) + m11 * bf2f(v11b[j]);
            bf0[j] = f2bf(s0);
            bf1[j] = f2bf(s1);
        }

        // 4 m-tiles x 2 kc MFMAs: o = 0..63
        const short* apb = dwbf + (size_t)(t * 64 + arow) * 64 + kseg * 8;
        #pragma unroll
        for (int m = 0; m < 4; ++m) {
            const bf8 a0 = *(const bf8*)(apb + m * 16 * 64);
            const bf8 a1 = *(const bf8*)(apb + m * 16 * 64 + 32);
            oacc[m] = __builtin_amdgcn_mfma_f32_16x16x32_bf16(a0, bf0, oacc[m], 0, 0, 0);
            oacc[m] = __builtin_amdgcn_mfma_f32_16x16x32_bf16(a1, bf1, oacc[m], 0, 0, 0);
        }
    }

    // ---------------- epilogue: o = m*16 + kseg*4 + r ----------------------
    float* ob = out + (size_t)b * COUT_ * HW_ + pix;
    #pragma unroll
    for (int m = 0; m < 4; ++m)
        #pragma unroll
        for (int r = 0; r < 4; ++r) {
            const int o = m * 16 + kseg * 4 + r;
            ob[(size_t)o * HW_] = oacc[m][r] + dbias[o];
        }
}

extern "C" void kernel_launch(void* const* d_in, const int* in_sizes, int n_in,
                              void* d_out, int out_size, void* d_ws, size_t ws_size,
                              hipStream_t stream) {
    const float* x        = (const float*)d_in[0];
    const float* offset_w = (const float*)d_in[1];
    const float* offset_b = (const float*)d_in[2];
    const float* deform_w = (const float*)d_in[3];
    const float* deform_b = (const float*)d_in[4];
    float* out = (float*)d_out;

    short* dwbf = (short*)d_ws;                        // 73728 B
    short* owbf = (short*)((char*)d_ws + 73728);       // 36864 B
    short* xt   = (short*)((char*)d_ws + 110592);      // 8 MB NHWC bf16

    prep_all<<<1024 + 144, 256, 0, stream>>>(x, offset_w, deform_w, xt, dwbf, owbf);

    dim3 grid(HW_ / TILE_, B_);
    fused_deform_mfma<<<grid, 256, 0, stream>>>(xt, owbf, offset_b, dwbf, deform_b, out);
}

// Round 8
// 48.128 us; speedup vs baseline: 3.5912x; 2.2226x over previous
//
#include <hip/hip_runtime.h>
#include <hip/hip_bf16.h>

#define B_    4
#define CIN_  64
#define H_    128
#define W_    128
#define COUT_ 64
#define KK_   9
#define OFFC_ 18
#define HW_   (H_*W_)
#define TILE_ 64

typedef short bf8  __attribute__((ext_vector_type(8)));   // 8 bf16 (4 VGPRs)
typedef float f32x4 __attribute__((ext_vector_type(4)));

__device__ inline short f2bf(float f) {
    union { __hip_bfloat16 h; short s; } u; u.h = __float2bfloat16(f); return u.s;
}
__device__ inline float bf2f(short s) {
    union { unsigned u; float f; } v; v.u = ((unsigned)(unsigned short)s) << 16; return v.f;
}

// ---------------------------------------------------------------------------
// Prep (single launch): blocks 0..1023 transpose x -> NHWC bf16;
// blocks 1024..1167 repack weights to bf16 MFMA layout.
//   xt[b][y][x][c]   dwbf[k][o][c] (9*64*64)   owbf[k][co<32][c] (pad rows 0)
// ---------------------------------------------------------------------------
__global__ __launch_bounds__(256) void prep_all(
    const float* __restrict__ x,
    const float* __restrict__ ow, const float* __restrict__ dw,
    short* __restrict__ xt, short* __restrict__ dwbf, short* __restrict__ owbf)
{
    const int tid = threadIdx.x;
    const int bid = blockIdx.x;
    if (bid < 1024) {
        const int b  = bid >> 8;
        const int pb = bid & 255;
        const int p  = tid & 63;
        const int g  = tid >> 6;             // channel group 0..3 (16 ch)
        const int pix = pb * 64 + p;
        const float* src = x + ((size_t)b * CIN_ + g * 16) * HW_ + pix;
        short vals[16];
        #pragma unroll
        for (int j = 0; j < 16; ++j) vals[j] = f2bf(src[(size_t)j * HW_]);
        short* dst = xt + ((size_t)b * HW_ + pix) * 64 + g * 16;
        *(bf8*)dst       = *(bf8*)&vals[0];
        *(bf8*)(dst + 8) = *(bf8*)&vals[8];
    } else {
        const int idx = (bid - 1024) * 256 + tid;   // 0..36863
        {   // dwbf: 9*64*64 = 36864
            const int k = idx / (COUT_ * CIN_);
            const int r = idx % (COUT_ * CIN_);
            const int o = r >> 6, c = r & 63;
            dwbf[idx] = f2bf(dw[(o * CIN_ + c) * KK_ + k]);
        }
        if (idx < KK_ * 32 * CIN_) {                // 18432
            const int k = idx / (32 * CIN_);
            const int r = idx % (32 * CIN_);
            const int co = r >> 6, c = r & 63;
            owbf[idx] = f2bf(co < OFFC_ ? ow[(co * CIN_ + c) * KK_ + k] : 0.0f);
        }
    }
}

// ---------------------------------------------------------------------------
// Fused kernel. Block = 256 thr (4 waves) = 64 pixels (half row).
// grid: 1024 blocks (1D), XCD-swizzled so each XCD works on a contiguous
// 128-block chunk (~1 MB of xt -> L2-resident).
// Phase A: offset conv via MFMA from LDS-staged patch (chunk-XOR swizzle).
// Phase B: software-pipelined: loads(t+1) -> MFMA(t) -> combine+write(t+1).
// Staging lanes: 4 lanes cover one pixel's 64 B channel row per corner.
// ---------------------------------------------------------------------------
__global__ __launch_bounds__(256, 4) void fused_deform_mfma(
    const short* __restrict__ xt,    // (B,HW,64) bf16 channels-last
    const short* __restrict__ owbf,  // [9][32][64] bf16
    const float* __restrict__ obias, // (18,)
    const short* __restrict__ dwbf,  // [9][64][64] bf16
    const float* __restrict__ dbias, // (64,)
    float* __restrict__ out)         // (B,64,128,128) f32
{
    __shared__ union {
        short xtl[3 * 66 * 64];      // phase A: [y][q][c], q = col+1 (25.3 KB)
        short smp[2 * 64 * 64];      // phase B: [buf][p][c]           (16 KB)
    } u;
    __shared__ float offs[OFFC_ * TILE_];

    // ---- XCD-aware block swizzle (1024 % 8 == 0 -> simple bijection) ----
    const int lin  = blockIdx.x;
    const int nid  = (lin & 7) * 128 + (lin >> 3);
    const int b    = nid >> 8;
    const int tile = nid & 255;

    const int tid = threadIdx.x;
    const int pixbase = tile * TILE_;
    const int ho    = pixbase >> 7;
    const int wbase = pixbase & (W_ - 1);
    const int lane  = tid & 63;
    const int wv    = tid >> 6;              // wave 0..3
    const int arow  = lane & 15;             // MFMA frag row/col index
    const int kseg  = lane >> 4;             // 0..3

    const short* xbt = xt + (size_t)b * HW_ * 64;

    // ---- stage x patch (3 rows x 66 cols x 64 ch) once, swizzled ----
    for (int base = 0; base < 3 * 66 * 8; base += 256) {
        const int idx = base + tid;
        if (idx < 3 * 66 * 8) {
            const int cc = idx & 7;          // c-chunk
            const int qy = idx >> 3;         // 0..197
            const int y  = qy / 66;
            const int q  = qy - y * 66;
            const int gy = ho + y - 1;
            const int gx = wbase + q - 1;
            bf8 v;
            if (gy >= 0 && gy < H_ && gx >= 0 && gx < W_) {
                v = *(const bf8*)&xbt[(size_t)(gy * W_ + gx) * 64 + cc * 8];
            } else {
                #pragma unroll
                for (int j = 0; j < 8; ++j) v[j] = 0;
            }
            *(bf8*)&u.xtl[(y * 66 + q) * 64 + ((cc ^ (q & 7)) << 3)] = v;
        }
    }
    __syncthreads();

    // ---- Phase A: offset conv via MFMA ----
    {
        const int m = wv & 1;                // co tile
        const int h = wv >> 1;               // pixel half
        f32x4 acca[2];
        acca[0] = (f32x4)0.f; acca[1] = (f32x4)0.f;
        for (int t = 0; t < KK_; ++t) {
            const int ky = t / 3, kx = t % 3;
            #pragma unroll
            for (int kc = 0; kc < 2; ++kc) {
                const int cbase = kc * 32 + kseg * 8;
                const bf8 afrag = *(const bf8*)&owbf[(t * 32 + m * 16 + arow) * 64 + cbase];
                const int cchunk = cbase >> 3;
                #pragma unroll
                for (int nt = 0; nt < 2; ++nt) {
                    const int pp = h * 32 + nt * 16 + arow;
                    const int q = pp + kx;
                    const bf8 bfrag = *(const bf8*)&u.xtl[(ky * 66 + q) * 64 + ((cchunk ^ (q & 7)) << 3)];
                    acca[nt] = __builtin_amdgcn_mfma_f32_16x16x32_bf16(afrag, bfrag, acca[nt], 0, 0, 0);
                }
            }
        }
        #pragma unroll
        for (int nt = 0; nt < 2; ++nt) {
            #pragma unroll
            for (int r = 0; r < 4; ++r) {
                const int co = m * 16 + kseg * 4 + r;
                if (co < OFFC_) {
                    const int pp = h * 32 + nt * 16 + arow;
                    offs[co * TILE_ + pp] = acca[nt][r] + obias[co];
                }
            }
        }
    }
    __syncthreads();   // offs ready; xtl dead -> smp may reuse the union

    // ---- Phase B: pipelined deformable conv ----
    // Staging lane role: 4 lanes per pixel (sub = 16B chunk of channel row).
    const int pix16 = lane >> 2;             // 0..15 pixel within wave
    const int sub   = lane & 3;              // channel sub-chunk
    const int p     = wv * 16 + pix16;       // pixel 0..63
    const int wo    = wbase + p;

    bf8 r00a, r00b, r01a, r01b, r10a, r10b, r11a, r11b;
    float pm00, pm01, pm10, pm11;

    auto loadB = [&](int t) {
        const int ky = t / 3, kx = t % 3;
        const float dy = offs[(2 * t + 0) * TILE_ + p];
        const float dx = offs[(2 * t + 1) * TILE_ + p];
        const float ys = (float)(ho + ky - 1) + dy;
        const float xs = (float)(wo + kx - 1) + dx;
        const float y0f = floorf(ys), x0f = floorf(xs);
        const float ly = ys - y0f, lx = xs - x0f;
        const int y0 = (int)y0f, x0 = (int)x0f;
        const int y1 = y0 + 1,   x1 = x0 + 1;
        const bool y0v = (y0 >= 0) & (y0 < H_);
        const bool y1v = (y1 >= 0) & (y1 < H_);
        const bool x0v = (x0 >= 0) & (x0 < W_);
        const bool x1v = (x1 >= 0) & (x1 < W_);
        pm00 = (y0v & x0v) ? (1.f - ly) * (1.f - lx) : 0.f;
        pm01 = (y0v & x1v) ? (1.f - ly) * lx         : 0.f;
        pm10 = (y1v & x0v) ? ly * (1.f - lx)         : 0.f;
        pm11 = (y1v & x1v) ? ly * lx                 : 0.f;
        const int y0c = min(max(y0, 0), H_ - 1);
        const int y1c = min(max(y1, 0), H_ - 1);
        const int x0c = min(max(x0, 0), W_ - 1);
        const int x1c = min(max(x1, 0), W_ - 1);
        const short* c00 = xbt + (size_t)(y0c * W_ + x0c) * 64 + sub * 8;
        const short* c01 = xbt + (size_t)(y0c * W_ + x1c) * 64 + sub * 8;
        const short* c10 = xbt + (size_t)(y1c * W_ + x0c) * 64 + sub * 8;
        const short* c11 = xbt + (size_t)(y1c * W_ + x1c) * 64 + sub * 8;
        r00a = *(const bf8*)(c00); r00b = *(const bf8*)(c00 + 32);
        r01a = *(const bf8*)(c01); r01b = *(const bf8*)(c01 + 32);
        r10a = *(const bf8*)(c10); r10b = *(const bf8*)(c10 + 32);
        r11a = *(const bf8*)(c11); r11b = *(const bf8*)(c11 + 32);
    };

    auto combineWrite = [&](int dstbuf) {
        bf8 va, vb;
        #pragma unroll
        for (int j = 0; j < 8; ++j) {
            const float sa = pm00 * bf2f(r00a[j]) + pm01 * bf2f(r01a[j])
                           + pm10 * bf2f(r10a[j]) + pm11 * bf2f(r11a[j]);
            const float sb = pm00 * bf2f(r00b[j]) + pm01 * bf2f(r01b[j])
                           + pm10 * bf2f(r10b[j]) + pm11 * bf2f(r11b[j]);
            va[j] = f2bf(sa);
            vb[j] = f2bf(sb);
        }
        const int cA = sub;                  // channels sub*8 .. +8
        const int cB = sub + 4;              // channels 32+sub*8 .. +8
        *(bf8*)&u.smp[dstbuf * 4096 + p * 64 + ((cA ^ (p & 7)) << 3)] = va;
        *(bf8*)&u.smp[dstbuf * 4096 + p * 64 + ((cB ^ (p & 7)) << 3)] = vb;
    };

    f32x4 accb[4];
    #pragma unroll
    for (int nt = 0; nt < 4; ++nt) accb[nt] = (f32x4)0.f;

    int buf = 0;
    loadB(0);
    combineWrite(0);
    __syncthreads();
    for (int t = 0; t < KK_; ++t) {
        if (t < KK_ - 1) loadB(t + 1);       // issue gathers early
        #pragma unroll
        for (int kc = 0; kc < 2; ++kc) {
            const int cbase = kc * 32 + kseg * 8;
            const bf8 afrag = *(const bf8*)&dwbf[(t * 64 + wv * 16 + arow) * 64 + cbase];
            const int cchunk = cbase >> 3;
            #pragma unroll
            for (int nt = 0; nt < 4; ++nt) {
                const int pp = nt * 16 + arow;
                const bf8 bfrag = *(const bf8*)&u.smp[buf * 4096 + pp * 64 + ((cchunk ^ (pp & 7)) << 3)];
                accb[nt] = __builtin_amdgcn_mfma_f32_16x16x32_bf16(afrag, bfrag, accb[nt], 0, 0, 0);
            }
        }
        if (t < KK_ - 1) combineWrite(buf ^ 1);  // convert+write after MFMAs
        __syncthreads();
        buf ^= 1;
    }

    // ---- epilogue: o = wv*16 + kseg*4 + r, pixel = pixbase + pp ----
    float* ob = out + (size_t)b * COUT_ * HW_ + pixbase;
    #pragma unroll
    for (int nt = 0; nt < 4; ++nt) {
        const int pp = nt * 16 + arow;
        #pragma unroll
        for (int r = 0; r < 4; ++r) {
            const int o = wv * 16 + kseg * 4 + r;
            ob[(size_t)o * HW_ + pp] = accb[nt][r] + dbias[o];
        }
    }
}

extern "C" void kernel_launch(void* const* d_in, const int* in_sizes, int n_in,
                              void* d_out, int out_size, void* d_ws, size_t ws_size,
                              hipStream_t stream) {
    const float* x        = (const float*)d_in[0];
    const float* offset_w = (const float*)d_in[1];
    const float* offset_b = (const float*)d_in[2];
    const float* deform_w = (const float*)d_in[3];
    const float* deform_b = (const float*)d_in[4];
    float* out = (float*)d_out;

    short* dwbf = (short*)d_ws;                        // 73728 B
    short* owbf = (short*)((char*)d_ws + 73728);       // 36864 B
    short* xt   = (short*)((char*)d_ws + 110592);      // 8 MB NHWC bf16

    prep_all<<<1024 + 144, 256, 0, stream>>>(x, offset_w, deform_w, xt, dwbf, owbf);

    fused_deform_mfma<<<1024, 256, 0, stream>>>(xt, owbf, offset_b, dwbf, deform_b, out);
}